// Round 3
// baseline (337.650 us; speedup 1.0000x reference)
//
#include <hip/hip_runtime.h>

#define D 128          // D_IN == D_OUT == 128
#define NREL 4
#define BINSHIFT 8     // 256 buckets per coarse bin
#define NBK 256        // buckets per bin
#define BCAP 1664      // edge capacity per bin window (mean 1280, +10.7 sigma)
#define CH 4096        // edges per part1 chunk
#define NBINS_MAX 1600
#define BPT 7          // bins per thread in part1 scan (7*256 >= 1600)

typedef __attribute__((ext_vector_type(8))) short short8;
typedef __attribute__((ext_vector_type(4))) float f32x4;

static __device__ inline unsigned short f2bf(float f) {
    unsigned int u = __float_as_uint(f);
    u += 0x7fffu + ((u >> 16) & 1u);   // round-to-nearest-even
    return (unsigned short)(u >> 16);
}

// ---------------------------------------------------------------------------
// part1 + prep fused. Bucket key is DST-MAJOR: g = dst*4 + rel, so one bin
// (256 buckets) = 64 dsts x 4 rels = one M=64, K=512 output tile.
//  A) blocks with a chunk: LDS counting-sort of 4096 edges over 1563 coarse
//     bins -> DEST-ORDER global writes (coalesced runs) into per-bin windows.
//  B) all blocks: grid-stride xcast (f32->bf16), W swizzle, bias sum.
// Entry = src | (g&255)<<17, bin = g>>8.
// ---------------------------------------------------------------------------
__global__ __launch_bounds__(256) void part1prep_kernel(
    const float* __restrict__ x,      // [N][128]
    const float* __restrict__ W,      // [4][128][128]
    const float* __restrict__ bias,   // [4][128]
    const int* __restrict__ src, const int* __restrict__ dst,
    int* __restrict__ binCnt, unsigned int* __restrict__ part,
    unsigned short* __restrict__ xB,  // [N][128] bf16
    unsigned short* __restrict__ Wsw, // [16][8][64][8] bf16
    float* __restrict__ bsum,         // [128]
    int E, int N, int nbins, int total)
{
    __shared__ unsigned int   sh_e[CH];     // 16 KB entries
    __shared__ unsigned short sh_b[CH];     //  8 KB bin ids
    __shared__ unsigned short sh_inv[CH];   //  8 KB rank -> chunk index
    __shared__ int hist[NBINS_MAX];         //  6.4 KB (count -> cursor)
    __shared__ int offl[NBINS_MAX];         //  6.4 KB local exclusive offsets
    __shared__ int basel[NBINS_MAX];        //  6.4 KB global bases
    __shared__ int scanb[256];

    const int t  = threadIdx.x;
    const int E2 = 2 * E, E3 = 3 * E;
    const int nchunks = (total + CH - 1) / CH;

    // ================= Phase A: partition (blocks with a chunk) =============
    if (blockIdx.x < nchunks) {
        const int e0 = blockIdx.x * CH;
        const int n  = min(CH, total - e0);

        for (int i = t; i < nbins; i += 256) hist[i] = 0;
        __syncthreads();

        for (int i = t; i < n; i += 256) {
            const int e = e0 + i;
            const int r = (e >= E) + (e >= E2) + (e >= E3);
            const int g = (dst[e] << 2) | r;           // DST-MAJOR key
            sh_e[i] = (unsigned)src[e] | ((unsigned)(g & (NBK - 1)) << 17);
            const int bin = g >> BINSHIFT;
            sh_b[i] = (unsigned short)bin;
            atomicAdd(&hist[bin], 1);
        }
        __syncthreads();

        // scan 1563 bins: BPT serial per thread + 256-wide block scan
        int loc[BPT];
        int run = 0;
        #pragma unroll
        for (int k = 0; k < BPT; ++k) {
            const int b = t * BPT + k;
            loc[k] = run;
            run += (b < nbins) ? hist[b] : 0;
        }
        scanb[t] = run;
        __syncthreads();
        for (int off = 1; off < 256; off <<= 1) {
            int v = (t >= off) ? scanb[t - off] : 0;
            __syncthreads();
            scanb[t] += v;
            __syncthreads();
        }
        const int excl = scanb[t] - run;
        #pragma unroll
        for (int k = 0; k < BPT; ++k) {
            const int b = t * BPT + k;
            if (b < nbins) {
                offl[b] = excl + loc[k];
                const int h = hist[b];
                basel[b] = h ? (b * BCAP + atomicAdd(&binCnt[b], h)) : 0;
                hist[b] = 0;          // reuse as cursor
            }
        }
        __syncthreads();

        // rank: sh_inv[sorted_pos] = chunk index
        for (int i = t; i < n; i += 256) {
            const int bin = sh_b[i];
            const int p = offl[bin] + atomicAdd(&hist[bin], 1);
            sh_inv[p] = (unsigned short)i;
        }
        __syncthreads();

        // dest-order write: consecutive j -> consecutive addresses per run
        for (int j = t; j < n; j += 256) {
            const int i   = sh_inv[j];
            const int bin = sh_b[i];
            const int dest = basel[bin] + (j - offl[bin]);
            if (dest < (bin + 1) * BCAP)   // 10.7-sigma guard
                part[dest] = sh_e[i];
        }
    }

    // ================= Phase B: prep (all blocks, grid-stride) ==============
    const int gtid  = blockIdx.x * 256 + t;
    const int gsize = gridDim.x * 256;

    if (gtid < D)
        bsum[gtid] = bias[gtid] + bias[D + gtid] + bias[2 * D + gtid] + bias[3 * D + gtid];

    for (int gid = gtid; gid < 8192; gid += gsize) {
        const int l   = gid & 63;
        const int ct  = (gid >> 6) & 7;
        const int kb  = gid >> 9;
        const int rel = kb >> 2;
        const int kbase = (kb & 3) * 32 + (l >> 4) * 8;
        const int nn = ct * 16 + (l & 15);
        ushort4 v0, v1;
        const float* wp = W + (size_t)rel * D * D + (size_t)kbase * D + nn;
        v0.x = f2bf(wp[0 * D]); v0.y = f2bf(wp[1 * D]);
        v0.z = f2bf(wp[2 * D]); v0.w = f2bf(wp[3 * D]);
        v1.x = f2bf(wp[4 * D]); v1.y = f2bf(wp[5 * D]);
        v1.z = f2bf(wp[6 * D]); v1.w = f2bf(wp[7 * D]);
        ushort4* op = (ushort4*)(Wsw + (size_t)gid * 8);
        op[0] = v0;
        op[1] = v1;
    }

    const int n4 = N * D / 4;
    for (int i = gtid; i < n4; i += gsize) {
        const float4 v = ((const float4*)x)[i];
        ushort4 o;
        o.x = f2bf(v.x); o.y = f2bf(v.y); o.z = f2bf(v.z); o.w = f2bf(v.w);
        ((ushort4*)xB)[i] = o;
    }
}

// ---------------------------------------------------------------------------
// Fused aggregate + GEMM + bias + ReLU. ONE block per bin (M=64 dsts).
//  A) read part[] ONCE: histogram 256 buckets + stage raw entries into the
//     (still-idle) agg LDS region; scan; sort LDS->global srt window.
//  B/C) 4 rel-quarters: gather rel q's 64 buckets (srt ids software-
//     pipelined from L2) -> bf16 LDS tile agg[64][128] (XOR-swizzled), sync,
//     4-kb MFMA pass accumulating into persistent VGPR acc[4][2], sync.
//  Epilogue: bias + ReLU + f32 store.
// LDS 19.5 KB -> 8 blocks/CU (wave-limit cap, 100% occupancy ceiling).
// __launch_bounds__(256,8) pins VGPR<=64 so residency isn't register-capped.
// ---------------------------------------------------------------------------
__global__ __launch_bounds__(256, 8) void agg_gemm_kernel(
    const unsigned int* __restrict__ part,
    unsigned int* __restrict__ srt,          // [nbins][BCAP] sorted src ids
    const int* __restrict__ binCnt,
    const unsigned short* __restrict__ xB,   // [N][128] bf16
    const unsigned short* __restrict__ Wsw,  // [16][8][64][8] bf16
    const float* __restrict__ bsum,          // [128]
    float* __restrict__ out,                 // [N][128]
    int N)
{
    __shared__ int hist[NBK];                          // 1 KB
    __shared__ int scanbuf[NBK];                       // 1 KB
    __shared__ int offl[NBK + 1];                      // 1 KB
    __shared__ __align__(16) unsigned short agg[64 * 128];  // 16 KB, swizzled
    // phase-A overlay: raw entry staging in the idle agg region
    unsigned int* raw = (unsigned int*)agg;            // holds <= BCAP uints

    const int t    = threadIdx.x;
    const int b    = blockIdx.x;
    const int base = b * BCAP;
    const int cnt  = min(binCnt[b], BCAP);
    const int dst0 = b * 64;

    // ---- A: histogram + raw staging (single part[] read) ----
    hist[t] = 0;
    __syncthreads();
    for (int i = t; i < cnt; i += 256) {
        const unsigned v = part[base + i];
        raw[i] = v;
        atomicAdd(&hist[v >> 17], 1);
    }
    __syncthreads();

    const int myc = hist[t];
    scanbuf[t] = myc;
    __syncthreads();
    for (int off = 1; off < 256; off <<= 1) {
        int v = (t >= off) ? scanbuf[t - off] : 0;
        __syncthreads();
        scanbuf[t] += v;
        __syncthreads();
    }
    offl[t] = scanbuf[t] - myc;
    if (t == 255) offl[256] = scanbuf[255];
    hist[t] = scanbuf[t] - myc;           // cursor
    __syncthreads();

    // sort: LDS raw -> global srt window (block-local, L2-resident)
    for (int i = t; i < cnt; i += 256) {
        const unsigned v = raw[i];
        const int pos = atomicAdd(&hist[v >> 17], 1);
        srt[base + pos] = v & 0x1FFFFu;
    }
    __syncthreads();   // drains vmcnt; srt visible block-wide; raw now dead

    // ---- B/C: 4 rel-quarters of gather -> LDS -> MFMA ----
    const int c    = t & 15;        // 16-byte chunk index (8 bf16)
    const int team = t >> 4;        // unit slot 0..15

    const int wv   = t >> 6;
    const int l    = t & 63;
    const int lrow = l & 15;
    const int quad = l >> 4;
    const int ct0  = wv * 2;        // each wave: 2 col-tiles x 4 row-tiles

    f32x4 acc[4][2] = {};

    #define ACCUM(v)                                        \
        accL[0] += __uint_as_float((v).x << 16);            \
        accH[0] += __uint_as_float((v).x & 0xffff0000u);    \
        accL[1] += __uint_as_float((v).y << 16);            \
        accH[1] += __uint_as_float((v).y & 0xffff0000u);    \
        accL[2] += __uint_as_float((v).z << 16);            \
        accH[2] += __uint_as_float((v).z & 0xffff0000u);    \
        accL[3] += __uint_as_float((v).w << 16);            \
        accH[3] += __uint_as_float((v).w & 0xffff0000u);

    #pragma unroll 1
    for (int q = 0; q < NREL; ++q) {
        if (q) __syncthreads();           // previous MFMA pass done with agg

        // gather rel q: 64 units (local dst), bucket = ld*4 + q
        for (int ld = team; ld < 64; ld += 16) {
            const int bkt = ld * 4 + q;
            const int beg = offl[bkt];
            const int end = offl[bkt + 1];
            const float inv = 1.0f / fmaxf((float)(end - beg), 1.0f);

            float accL[4] = {0.f, 0.f, 0.f, 0.f};
            float accH[4] = {0.f, 0.f, 0.f, 0.f};

            int j = beg;
            unsigned n0 = 0, n1 = 0, n2 = 0, n3 = 0;
            if (j + 3 < end) {
                n0 = srt[base + j];     n1 = srt[base + j + 1];
                n2 = srt[base + j + 2]; n3 = srt[base + j + 3];
            }
            for (; j + 3 < end; j += 4) {
                const uint4 v0 = *(const uint4*)(xB + (size_t)n0 * D + c * 8);
                const uint4 v1 = *(const uint4*)(xB + (size_t)n1 * D + c * 8);
                const uint4 v2 = *(const uint4*)(xB + (size_t)n2 * D + c * 8);
                const uint4 v3 = *(const uint4*)(xB + (size_t)n3 * D + c * 8);
                if (j + 7 < end) {      // prefetch next group while xB in flight
                    n0 = srt[base + j + 4]; n1 = srt[base + j + 5];
                    n2 = srt[base + j + 6]; n3 = srt[base + j + 7];
                }
                ACCUM(v0) ACCUM(v1) ACCUM(v2) ACCUM(v3)
            }
            for (; j < end; ++j) {
                const uint4 v0 = *(const uint4*)(xB + (size_t)srt[base + j] * D + c * 8);
                ACCUM(v0)
            }

            uint4 o;
            o.x = ((unsigned)f2bf(accH[0] * inv) << 16) | f2bf(accL[0] * inv);
            o.y = ((unsigned)f2bf(accH[1] * inv) << 16) | f2bf(accL[1] * inv);
            o.z = ((unsigned)f2bf(accH[2] * inv) << 16) | f2bf(accL[2] * inv);
            o.w = ((unsigned)f2bf(accH[3] * inv) << 16) | f2bf(accL[3] * inv);
            // row ld (256 B stride), chunk c, XOR-swizzled per row
            const int byte = (c * 16) ^ ((ld & 7) << 4);
            *(uint4*)((char*)agg + ld * 256 + byte) = o;
        }
        __syncthreads();

        // MFMA pass: K-quarter q = kb q*4 .. q*4+3
        #pragma unroll
        for (int kbl = 0; kbl < 4; ++kbl) {
            short8 a[4];
            #pragma unroll
            for (int rt = 0; rt < 4; ++rt) {
                const int row  = rt * 16 + lrow;
                const int byte = (kbl * 64 + quad * 16) ^ ((row & 7) << 4);
                a[rt] = *(const short8*)((const char*)agg + row * 256 + byte);
            }
            const int kb = q * 4 + kbl;
            const unsigned short* wp = Wsw + ((size_t)(kb * 8 + ct0) * 64 + l) * 8;
            const short8 b0 = *(const short8*)wp;
            const short8 b1 = *(const short8*)(wp + 64 * 8);
            #pragma unroll
            for (int rt = 0; rt < 4; ++rt) {
                acc[rt][0] = __builtin_amdgcn_mfma_f32_16x16x32_bf16(a[rt], b0, acc[rt][0], 0, 0, 0);
                acc[rt][1] = __builtin_amdgcn_mfma_f32_16x16x32_bf16(a[rt], b1, acc[rt][1], 0, 0, 0);
            }
        }
    }
    #undef ACCUM

    // ---- epilogue: bias + ReLU + store ----
    #pragma unroll
    for (int ci = 0; ci < 2; ++ci) {
        const int col = (ct0 + ci) * 16 + lrow;
        const float bv = bsum[col];
        #pragma unroll
        for (int rt = 0; rt < 4; ++rt) {
            #pragma unroll
            for (int e = 0; e < 4; ++e) {
                const int row = dst0 + rt * 16 + quad * 4 + e;
                if (row < N)
                    out[(size_t)row * D + col] = fmaxf(acc[rt][ci][e] + bv, 0.f);
            }
        }
    }
}

static inline size_t align_up(size_t v, size_t a) { return (v + a - 1) & ~(a - 1); }

extern "C" void kernel_launch(void* const* d_in, const int* in_sizes, int n_in,
                              void* d_out, int out_size, void* d_ws, size_t ws_size,
                              hipStream_t stream)
{
    const float* x    = (const float*)d_in[0];   // [N, 128]
    const float* W    = (const float*)d_in[1];   // [4, 128, 128]
    const float* bias = (const float*)d_in[2];   // [4, 128]
    const int* src    = (const int*)d_in[3];     // [4, E]
    const int* dst    = (const int*)d_in[4];     // [4, E]
    float* out        = (float*)d_out;           // [N, 128]

    const int N = in_sizes[0] / D;               // 100000
    const int E = in_sizes[3] / NREL;            // 500000
    const int nG = NREL * N;                     // 400000 buckets
    const int totalE = NREL * E;                 // 2000000 edges
    const int nbins  = (nG + NBK - 1) >> BINSHIFT;  // 1563

    char* w = (char*)d_ws;
    int* binCnt = (int*)w;            w += align_up((size_t)nbins * 4, 256);
    unsigned int* part = (unsigned int*)w;     w += align_up((size_t)nbins * BCAP * 4, 256);
    unsigned short* Wsw = (unsigned short*)w;  w += align_up((size_t)512 * D * 2, 256);
    float* bsum = (float*)w;          w += align_up((size_t)D * 4, 256);
    unsigned short* xB = (unsigned short*)w;   w += align_up((size_t)N * D * 2, 256);
    unsigned int* srt = (unsigned int*)w;      // [nbins][BCAP] sorted src ids

    const int nchunks   = (totalE + CH - 1) / CH;   // 489
    const int p1_blocks = nchunks > 1024 ? nchunks : 1024;

    hipMemsetAsync(binCnt, 0, (size_t)nbins * sizeof(int), stream);
    part1prep_kernel<<<p1_blocks, 256, 0, stream>>>(
        x, W, bias, src, dst, binCnt, part, xB, Wsw, bsum, E, N, nbins, totalE);
    agg_gemm_kernel<<<nbins, 256, 0, stream>>>(part, srt, binCnt, xB, Wsw, bsum, out, N);
}

// Round 4
// 280.163 us; speedup vs baseline: 1.2052x; 1.2052x over previous
//
#include <hip/hip_runtime.h>

#define D 128          // D_IN == D_OUT == 128
#define NREL 4
#define BINSHIFT 8     // 256 buckets per coarse bin
#define NBK 256        // buckets per bin
#define BCAP 1664      // edge capacity per bin window (mean 1280, +10.7 sigma)
#define CH 4096        // edges per part1 chunk
#define NBINS_MAX 1600
#define BPT 7          // bins per thread in part1 scan (7*256 >= 1600)

typedef __attribute__((ext_vector_type(8))) short short8;
typedef __attribute__((ext_vector_type(4))) float f32x4;

static __device__ inline unsigned short f2bf(float f) {
    unsigned int u = __float_as_uint(f);
    u += 0x7fffu + ((u >> 16) & 1u);   // round-to-nearest-even
    return (unsigned short)(u >> 16);
}

// ---------------------------------------------------------------------------
// part1 + prep fused. Bucket key is DST-MAJOR: g = dst*4 + rel, so one bin
// (256 buckets) = 64 dsts x 4 rels = one M=64, K=512 output tile.
//  A) blocks with a chunk: LDS counting-sort of 4096 edges over 1563 coarse
//     bins -> DEST-ORDER global writes (coalesced runs) into per-bin windows.
//  B) all blocks: grid-stride xcast (f32->bf16), W swizzle, bias sum.
// Entry = src | (g&255)<<17, bin = g>>8.
// ---------------------------------------------------------------------------
__global__ __launch_bounds__(256) void part1prep_kernel(
    const float* __restrict__ x,      // [N][128]
    const float* __restrict__ W,      // [4][128][128]
    const float* __restrict__ bias,   // [4][128]
    const int* __restrict__ src, const int* __restrict__ dst,
    int* __restrict__ binCnt, unsigned int* __restrict__ part,
    unsigned short* __restrict__ xB,  // [N][128] bf16
    unsigned short* __restrict__ Wsw, // [16][8][64][8] bf16
    float* __restrict__ bsum,         // [128]
    int E, int N, int nbins, int total)
{
    __shared__ unsigned int   sh_e[CH];     // 16 KB entries
    __shared__ unsigned short sh_b[CH];     //  8 KB bin ids
    __shared__ unsigned short sh_inv[CH];   //  8 KB rank -> chunk index
    __shared__ int hist[NBINS_MAX];         //  6.4 KB (count -> cursor)
    __shared__ int offl[NBINS_MAX];         //  6.4 KB local exclusive offsets
    __shared__ int basel[NBINS_MAX];        //  6.4 KB global bases
    __shared__ int scanb[256];

    const int t  = threadIdx.x;
    const int E2 = 2 * E, E3 = 3 * E;
    const int nchunks = (total + CH - 1) / CH;

    // ================= Phase A: partition (blocks with a chunk) =============
    if (blockIdx.x < nchunks) {
        const int e0 = blockIdx.x * CH;
        const int n  = min(CH, total - e0);

        for (int i = t; i < nbins; i += 256) hist[i] = 0;
        __syncthreads();

        for (int i = t; i < n; i += 256) {
            const int e = e0 + i;
            const int r = (e >= E) + (e >= E2) + (e >= E3);
            const int g = (dst[e] << 2) | r;           // DST-MAJOR key
            sh_e[i] = (unsigned)src[e] | ((unsigned)(g & (NBK - 1)) << 17);
            const int bin = g >> BINSHIFT;
            sh_b[i] = (unsigned short)bin;
            atomicAdd(&hist[bin], 1);
        }
        __syncthreads();

        // scan 1563 bins: BPT serial per thread + 256-wide block scan
        int loc[BPT];
        int run = 0;
        #pragma unroll
        for (int k = 0; k < BPT; ++k) {
            const int b = t * BPT + k;
            loc[k] = run;
            run += (b < nbins) ? hist[b] : 0;
        }
        scanb[t] = run;
        __syncthreads();
        for (int off = 1; off < 256; off <<= 1) {
            int v = (t >= off) ? scanb[t - off] : 0;
            __syncthreads();
            scanb[t] += v;
            __syncthreads();
        }
        const int excl = scanb[t] - run;
        #pragma unroll
        for (int k = 0; k < BPT; ++k) {
            const int b = t * BPT + k;
            if (b < nbins) {
                offl[b] = excl + loc[k];
                const int h = hist[b];
                basel[b] = h ? (b * BCAP + atomicAdd(&binCnt[b], h)) : 0;
                hist[b] = 0;          // reuse as cursor
            }
        }
        __syncthreads();

        // rank: sh_inv[sorted_pos] = chunk index
        for (int i = t; i < n; i += 256) {
            const int bin = sh_b[i];
            const int p = offl[bin] + atomicAdd(&hist[bin], 1);
            sh_inv[p] = (unsigned short)i;
        }
        __syncthreads();

        // dest-order write: consecutive j -> consecutive addresses per run
        for (int j = t; j < n; j += 256) {
            const int i   = sh_inv[j];
            const int bin = sh_b[i];
            const int dest = basel[bin] + (j - offl[bin]);
            if (dest < (bin + 1) * BCAP)   // 10.7-sigma guard
                part[dest] = sh_e[i];
        }
    }

    // ================= Phase B: prep (all blocks, grid-stride) ==============
    const int gtid  = blockIdx.x * 256 + t;
    const int gsize = gridDim.x * 256;

    if (gtid < D)
        bsum[gtid] = bias[gtid] + bias[D + gtid] + bias[2 * D + gtid] + bias[3 * D + gtid];

    for (int gid = gtid; gid < 8192; gid += gsize) {
        const int l   = gid & 63;
        const int ct  = (gid >> 6) & 7;
        const int kb  = gid >> 9;
        const int rel = kb >> 2;
        const int kbase = (kb & 3) * 32 + (l >> 4) * 8;
        const int nn = ct * 16 + (l & 15);
        ushort4 v0, v1;
        const float* wp = W + (size_t)rel * D * D + (size_t)kbase * D + nn;
        v0.x = f2bf(wp[0 * D]); v0.y = f2bf(wp[1 * D]);
        v0.z = f2bf(wp[2 * D]); v0.w = f2bf(wp[3 * D]);
        v1.x = f2bf(wp[4 * D]); v1.y = f2bf(wp[5 * D]);
        v1.z = f2bf(wp[6 * D]); v1.w = f2bf(wp[7 * D]);
        ushort4* op = (ushort4*)(Wsw + (size_t)gid * 8);
        op[0] = v0;
        op[1] = v1;
    }

    const int n4 = N * D / 4;
    for (int i = gtid; i < n4; i += gsize) {
        const float4 v = ((const float4*)x)[i];
        ushort4 o;
        o.x = f2bf(v.x); o.y = f2bf(v.y); o.z = f2bf(v.z); o.w = f2bf(v.w);
        ((ushort4*)xB)[i] = o;
    }
}

// ---------------------------------------------------------------------------
// Fused aggregate + GEMM + bias + ReLU. ONE block per bin (M=64 dsts).
//  A) read part[] ONCE: histogram + raw staging into the idle agg region
//     (8 KB >= 6.7 KB); scan; LDS counting-sort into sh_s.
//  B/C) 2 half-tiles (M=32) x 4 rel-quarters: gather rel q of half h ->
//     bf16 LDS tile agg[32][128] (XOR-swizzled), sync, 4-kb MFMA pass into
//     per-half VGPR acc[2][2], sync; per-half epilogue (bias+ReLU+store).
// LDS 17.9 KB -> 8 blocks/CU (wave-limit cap). Edge list stays in LDS, so
// traffic returns to the round-2 floor while keeping the 8-block residency.
// ---------------------------------------------------------------------------
__global__ __launch_bounds__(256, 8) void agg_gemm_kernel(
    const unsigned int* __restrict__ part,
    const int* __restrict__ binCnt,
    const unsigned short* __restrict__ xB,   // [N][128] bf16
    const unsigned short* __restrict__ Wsw,  // [16][8][64][8] bf16
    const float* __restrict__ bsum,          // [128]
    float* __restrict__ out,                 // [N][128]
    int N)
{
    __shared__ int sh_s[BCAP];                         // 6.7 KB sorted src
    __shared__ int hist[NBK];                          // 1 KB
    __shared__ int scanbuf[NBK];                       // 1 KB
    __shared__ int offl[NBK + 1];                      // 1 KB
    __shared__ __align__(16) unsigned short agg[32 * 128];  // 8 KB, swizzled
    // phase-A overlay: raw entry staging in the idle agg region (6.7 <= 8 KB)
    unsigned int* raw = (unsigned int*)agg;

    const int t    = threadIdx.x;
    const int b    = blockIdx.x;
    const int base = b * BCAP;
    const int cnt  = min(binCnt[b], BCAP);
    const int dst0 = b * 64;

    // ---- A: histogram + raw staging (single part[] read) ----
    hist[t] = 0;
    __syncthreads();
    for (int i = t; i < cnt; i += 256) {
        const unsigned v = part[base + i];
        raw[i] = v;
        atomicAdd(&hist[v >> 17], 1);
    }
    __syncthreads();

    const int myc = hist[t];
    scanbuf[t] = myc;
    __syncthreads();
    for (int off = 1; off < 256; off <<= 1) {
        int v = (t >= off) ? scanbuf[t - off] : 0;
        __syncthreads();
        scanbuf[t] += v;
        __syncthreads();
    }
    offl[t] = scanbuf[t] - myc;
    if (t == 255) offl[256] = scanbuf[255];
    hist[t] = scanbuf[t] - myc;           // cursor
    __syncthreads();

    // sort: LDS raw -> LDS sh_s
    for (int i = t; i < cnt; i += 256) {
        const unsigned v = raw[i];
        const int pos = atomicAdd(&hist[v >> 17], 1);
        sh_s[pos] = (int)(v & 0x1FFFF);
    }
    __syncthreads();

    // ---- B/C: 2 halves x 4 rel-quarters of gather -> LDS -> MFMA ----
    const int c    = t & 15;        // 16-byte chunk index (8 bf16)
    const int team = t >> 4;        // unit slot 0..15

    const int wv   = t >> 6;
    const int l    = t & 63;
    const int lrow = l & 15;
    const int quad = l >> 4;
    const int ct0  = wv * 2;        // each wave: 2 col-tiles x 2 row-tiles

    #define ACCUM(v)                                        \
        accL[0] += __uint_as_float((v).x << 16);            \
        accH[0] += __uint_as_float((v).x & 0xffff0000u);    \
        accL[1] += __uint_as_float((v).y << 16);            \
        accH[1] += __uint_as_float((v).y & 0xffff0000u);    \
        accL[2] += __uint_as_float((v).z << 16);            \
        accH[2] += __uint_as_float((v).z & 0xffff0000u);    \
        accL[3] += __uint_as_float((v).w << 16);            \
        accH[3] += __uint_as_float((v).w & 0xffff0000u);

    #pragma unroll 1
    for (int h = 0; h < 2; ++h) {
        f32x4 acc[2][2] = {};

        #pragma unroll 1
        for (int q = 0; q < NREL; ++q) {
            if (h | q) __syncthreads();   // previous MFMA pass done with agg

            // gather: 32 buckets of half h, rel q (bucket = (h*32+ld)*4+q)
            for (int ld = team; ld < 32; ld += 16) {
                const int bkt = (h * 32 + ld) * 4 + q;
                const int beg = offl[bkt];
                const int end = offl[bkt + 1];
                const float inv = 1.0f / fmaxf((float)(end - beg), 1.0f);

                float accL[4] = {0.f, 0.f, 0.f, 0.f};
                float accH[4] = {0.f, 0.f, 0.f, 0.f};

                int j = beg;
                for (; j + 3 < end; j += 4) {
                    const int s0 = sh_s[j];
                    const int s1 = sh_s[j + 1];
                    const int s2 = sh_s[j + 2];
                    const int s3 = sh_s[j + 3];
                    const uint4 v0 = *(const uint4*)(xB + (size_t)s0 * D + c * 8);
                    const uint4 v1 = *(const uint4*)(xB + (size_t)s1 * D + c * 8);
                    const uint4 v2 = *(const uint4*)(xB + (size_t)s2 * D + c * 8);
                    const uint4 v3 = *(const uint4*)(xB + (size_t)s3 * D + c * 8);
                    ACCUM(v0) ACCUM(v1) ACCUM(v2) ACCUM(v3)
                }
                for (; j < end; ++j) {
                    const uint4 v0 = *(const uint4*)(xB + (size_t)sh_s[j] * D + c * 8);
                    ACCUM(v0)
                }

                uint4 o;
                o.x = ((unsigned)f2bf(accH[0] * inv) << 16) | f2bf(accL[0] * inv);
                o.y = ((unsigned)f2bf(accH[1] * inv) << 16) | f2bf(accL[1] * inv);
                o.z = ((unsigned)f2bf(accH[2] * inv) << 16) | f2bf(accL[2] * inv);
                o.w = ((unsigned)f2bf(accH[3] * inv) << 16) | f2bf(accL[3] * inv);
                // row ld (256 B stride), chunk c, XOR-swizzled per row
                const int byte = (c * 16) ^ ((ld & 7) << 4);
                *(uint4*)((char*)agg + ld * 256 + byte) = o;
            }
            __syncthreads();

            // MFMA pass: K-quarter q = kb q*4 .. q*4+3, rows of half h
            #pragma unroll
            for (int kbl = 0; kbl < 4; ++kbl) {
                short8 a[2];
                #pragma unroll
                for (int rt = 0; rt < 2; ++rt) {
                    const int row  = rt * 16 + lrow;
                    const int byte = (kbl * 64 + quad * 16) ^ ((row & 7) << 4);
                    a[rt] = *(const short8*)((const char*)agg + row * 256 + byte);
                }
                const int kb = q * 4 + kbl;
                const unsigned short* wp = Wsw + ((size_t)(kb * 8 + ct0) * 64 + l) * 8;
                const short8 b0 = *(const short8*)wp;
                const short8 b1 = *(const short8*)(wp + 64 * 8);
                acc[0][0] = __builtin_amdgcn_mfma_f32_16x16x32_bf16(a[0], b0, acc[0][0], 0, 0, 0);
                acc[1][0] = __builtin_amdgcn_mfma_f32_16x16x32_bf16(a[1], b0, acc[1][0], 0, 0, 0);
                acc[0][1] = __builtin_amdgcn_mfma_f32_16x16x32_bf16(a[0], b1, acc[0][1], 0, 0, 0);
                acc[1][1] = __builtin_amdgcn_mfma_f32_16x16x32_bf16(a[1], b1, acc[1][1], 0, 0, 0);
            }
        }

        // ---- epilogue for half h: bias + ReLU + store ----
        #pragma unroll
        for (int ci = 0; ci < 2; ++ci) {
            const int col = (ct0 + ci) * 16 + lrow;
            const float bv = bsum[col];
            #pragma unroll
            for (int rt = 0; rt < 2; ++rt) {
                #pragma unroll
                for (int e = 0; e < 4; ++e) {
                    const int row = dst0 + h * 32 + rt * 16 + quad * 4 + e;
                    if (row < N)
                        out[(size_t)row * D + col] = fmaxf(acc[rt][ci][e] + bv, 0.f);
                }
            }
        }
    }
    #undef ACCUM
}

static inline size_t align_up(size_t v, size_t a) { return (v + a - 1) & ~(a - 1); }

extern "C" void kernel_launch(void* const* d_in, const int* in_sizes, int n_in,
                              void* d_out, int out_size, void* d_ws, size_t ws_size,
                              hipStream_t stream)
{
    const float* x    = (const float*)d_in[0];   // [N, 128]
    const float* W    = (const float*)d_in[1];   // [4, 128, 128]
    const float* bias = (const float*)d_in[2];   // [4, 128]
    const int* src    = (const int*)d_in[3];     // [4, E]
    const int* dst    = (const int*)d_in[4];     // [4, E]
    float* out        = (float*)d_out;           // [N, 128]

    const int N = in_sizes[0] / D;               // 100000
    const int E = in_sizes[3] / NREL;            // 500000
    const int nG = NREL * N;                     // 400000 buckets
    const int totalE = NREL * E;                 // 2000000 edges
    const int nbins  = (nG + NBK - 1) >> BINSHIFT;  // 1563

    char* w = (char*)d_ws;
    int* binCnt = (int*)w;            w += align_up((size_t)nbins * 4, 256);
    unsigned int* part = (unsigned int*)w;     w += align_up((size_t)nbins * BCAP * 4, 256);
    unsigned short* Wsw = (unsigned short*)w;  w += align_up((size_t)512 * D * 2, 256);
    float* bsum = (float*)w;          w += align_up((size_t)D * 4, 256);
    unsigned short* xB = (unsigned short*)w;   // [N][128] bf16

    const int nchunks   = (totalE + CH - 1) / CH;   // 489
    const int p1_blocks = nchunks > 1024 ? nchunks : 1024;

    hipMemsetAsync(binCnt, 0, (size_t)nbins * sizeof(int), stream);
    part1prep_kernel<<<p1_blocks, 256, 0, stream>>>(
        x, W, bias, src, dst, binCnt, part, xB, Wsw, bsum, E, N, nbins, totalE);
    agg_gemm_kernel<<<nbins, 256, 0, stream>>>(part, binCnt, xB, Wsw, bsum, out, N);
}